// Round 2
// baseline (662.868 us; speedup 1.0000x reference)
//
#include <hip/hip_runtime.h>

// SphereConv2DEXP: grid_sample(bilinear,zeros) + 3x3 conv stride 3 == implicit GEMM
//   M = 131072 (b,ho,wo), N = 256 (cout), K = 1152
// Round 2: ij-major K ordering (k' = ij*128 + ci) so the bilinear tap is
// constant across a K-step -> tap table read once per 4 K-steps from global
// (coalesced [ij][sp] planes), LDS table arrays deleted (they were the round-1
// bottleneck: 16 LDS reads/thread/step at 4-8 way bank conflict strides).

#define Hh   128
#define Ww   256
#define HWp  (Hh*Ww)        // 32768
#define CIN  128
#define COUT 256
#define KTOT 1152
#define NPTS (384*768)
#define BM   128
#define BN   256
#define BK   32
#define NKS  (KTOT/BK)      // 36

typedef __attribute__((ext_vector_type(8))) __bf16 bf16x8;
typedef __attribute__((ext_vector_type(4))) float  f32x4;

// ---------------------------------------------------------------------------
// Kernel 1: bilinear tap table, laid out as 9 planes [ij][sp] for coalesced
// per-K-step reads in the GEMM (lanes = consecutive sp).
// ---------------------------------------------------------------------------
__global__ void build_table(const float* __restrict__ grid,
                            int2* __restrict__ tI, float4* __restrict__ tW) {
    int g = blockIdx.x * 256 + threadIdx.x;
    if (g >= NPTS) return;
    int hh = g / 768, ww = g - hh * 768;
    int ho = hh / 3, ii = hh - 3 * ho;
    int wo = ww / 3, jj = ww - 3 * wo;

    float gx = grid[2 * g + 0];
    float gy = grid[2 * g + 1];
    float ix = ((gx + 1.0f) * (float)Ww - 1.0f) * 0.5f;
    float iy = ((gy + 1.0f) * (float)Hh - 1.0f) * 0.5f;
    float x0f = floorf(ix), y0f = floorf(iy);
    int x0 = (int)x0f, y0 = (int)y0f;
    float wx1 = ix - x0f, wx0 = 1.0f - wx1;
    float wy1 = iy - y0f, wy0 = 1.0f - wy1;

    float wyt = (y0 >= 0 && y0 < Hh) ? wy0 : 0.0f;
    float wyb = (y0 + 1 >= 0 && y0 + 1 < Hh) ? wy1 : 0.0f;
    int r0 = min(max(y0, 0), Hh - 1);
    int r1 = min(max(y0 + 1, 0), Hh - 1);

    int xb; float cw0, cw1;
    if (x0 < 0)            { xb = 0;      cw0 = wx1; cw1 = 0.0f; }
    else if (x0 > Ww - 2)  { xb = Ww - 2; cw0 = 0.0f; cw1 = wx0; }
    else                   { xb = x0;     cw0 = wx0; cw1 = wx1; }

    int e = (ii * 3 + jj) * HWp + (ho * Ww + wo);   // [ij][sp] planes
    tI[e] = make_int2(r0 * Ww + xb, r1 * Ww + xb);
    tW[e] = make_float4(cw0 * wyt, cw1 * wyt, cw0 * wyb, cw1 * wyb);
}

// ---------------------------------------------------------------------------
// Kernel 2: weight f32 -> bf16, retiled wt[ks][n][kk] under ij-major K:
//   k' = ks*32+kk, ij = ks>>2, ci = (ks&3)*32 + kk
// ---------------------------------------------------------------------------
__global__ void conv_w(const float* __restrict__ w, __bf16* __restrict__ wt) {
    int o = blockIdx.x * 256 + threadIdx.x;   // NKS*COUT*BK = 294912
    if (o >= NKS * COUT * BK) return;
    int kk = o & (BK - 1);
    int n  = (o >> 5) & (COUT - 1);
    int ks = o >> 13;
    int ci = ((ks & 3) << 5) + kk;
    int ij = ks >> 2;
    wt[o] = (__bf16)w[n * KTOT + ci * 9 + ij];
}

// ---------------------------------------------------------------------------
// Kernel 3: fused gather + bf16 MFMA GEMM.
// 512 thr (8 waves 2x4), tile 128x256, BK=32, wave tile 64x64, 16x16x32 MFMA.
// Outer loop over ij (9): one tap per thread; inner loop s (4 K-steps):
// 8 ci-planes gathered per thread as adjacent-pair float2 loads.
// ---------------------------------------------------------------------------
__global__ __launch_bounds__(512, 4) void sphconv_gemm(
    const float* __restrict__ x, const __bf16* __restrict__ wt,
    const float* __restrict__ bias, const int2* __restrict__ tI,
    const float4* __restrict__ tW, float* __restrict__ out) {

    __shared__ __align__(16) __bf16 sA[BM * 40];
    __shared__ __align__(16) __bf16 sB[BN * 40];

    const int t   = threadIdx.x;
    const int m0  = blockIdx.x * BM;
    const int b   = m0 >> 15;
    const int sp0 = m0 & (HWp - 1);
    const float* xb_ = x + (size_t)b * (CIN * HWp);

    const int lane = t & 63;
    const int wid  = t >> 6;
    const int wrow = wid >> 2;
    const int wcol = wid & 3;
    const int quad = lane >> 4;
    const int l16  = lane & 15;

    const int mr_s = t & 127;           // staging row (fixed sp)
    const int kg   = t >> 7;            // 0..3 -> kk base 8*kg
    const int sp   = sp0 + mr_s;

    const int nB   = t >> 1;            // B staging row
    const int kqB  = (t & 1) * 16;

    f32x4 acc[4][4];
#pragma unroll
    for (int r = 0; r < 4; ++r)
#pragma unroll
        for (int c = 0; c < 4; ++c) {
            f32x4 z = {0.0f, 0.0f, 0.0f, 0.0f};
            acc[r][c] = z;
        }

    for (int ij = 0; ij < 9; ++ij) {
        const int2   o  = tI[ij * HWp + sp];   // coalesced, L2-hot (7 MB table)
        const float4 wv = tW[ij * HWp + sp];

        for (int s = 0; s < 4; ++s) {
            const int ks = ij * 4 + s;

            // B stage: contiguous 16 KB chunk, 32 B per thread (issue first)
            const __bf16* srcB = wt + ks * (COUT * BK) + t * 16;
            bf16x8 v0 = *(const bf16x8*)(srcB);
            bf16x8 v1 = *(const bf16x8*)(srcB + 8);

            // A gather: 8 ci-planes, one bilinear sample each
            const float* img = xb_ + (size_t)((s << 5) + (kg << 3)) * HWp;
            bf16x8 av;
#pragma unroll
            for (int j = 0; j < 8; ++j) {
                float2 p0, p1;
                __builtin_memcpy(&p0, img + o.x, 8);
                __builtin_memcpy(&p1, img + o.y, 8);
                av[j] = (__bf16)(p0.x * wv.x + p0.y * wv.y +
                                 p1.x * wv.z + p1.y * wv.w);
                img += HWp;
            }

            *(bf16x8*)(&sA[mr_s * 40 + kg * 8]) = av;
            *(bf16x8*)(&sB[nB * 40 + kqB])      = v0;
            *(bf16x8*)(&sB[nB * 40 + kqB + 8])  = v1;
            __syncthreads();

            bf16x8 af[4], bfr[4];
#pragma unroll
            for (int r = 0; r < 4; ++r)
                af[r] = *(const bf16x8*)(&sA[(wrow * 64 + r * 16 + l16) * 40 + quad * 8]);
#pragma unroll
            for (int c = 0; c < 4; ++c)
                bfr[c] = *(const bf16x8*)(&sB[(wcol * 64 + c * 16 + l16) * 40 + quad * 8]);
#pragma unroll
            for (int r = 0; r < 4; ++r)
#pragma unroll
                for (int c = 0; c < 4; ++c)
                    acc[r][c] = __builtin_amdgcn_mfma_f32_16x16x32_bf16(
                        af[r], bfr[c], acc[r][c], 0, 0, 0);
            __syncthreads();
        }
    }

    // epilogue: D row=(quad*4+i), col=(lane&15)  [m89-verified layout]
#pragma unroll
    for (int c = 0; c < 4; ++c) {
        int n = wcol * 64 + c * 16 + l16;
        float bv = bias[n];
        float* outn = out + (((size_t)(b * COUT + n)) << 15) + sp0;
#pragma unroll
        for (int r = 0; r < 4; ++r) {
            int mbase = wrow * 64 + r * 16 + quad * 4;
#pragma unroll
            for (int i = 0; i < 4; ++i)
                outn[mbase + i] = acc[r][c][i] + bv;
        }
    }
}

// ---------------------------------------------------------------------------
extern "C" void kernel_launch(void* const* d_in, const int* in_sizes, int n_in,
                              void* d_out, int out_size, void* d_ws, size_t ws_size,
                              hipStream_t stream) {
    const float* x    = (const float*)d_in[0];
    const float* w    = (const float*)d_in[1];
    const float* bias = (const float*)d_in[2];
    const float* grid = (const float*)d_in[3];
    float* out = (float*)d_out;

    char* ws = (char*)d_ws;
    int2*   tI = (int2*)(ws);                       // 294912 * 8  = 2359296 B
    float4* tW = (float4*)(ws + 2359296);           // 294912 * 16 = 4718592 B
    __bf16* wt = (__bf16*)(ws + 7077888);           // 294912 * 2  =  589824 B

    build_table<<<(NPTS + 255) / 256, 256, 0, stream>>>(grid, tI, tW);
    conv_w<<<(NKS * COUT * BK + 255) / 256, 256, 0, stream>>>(w, wt);
    sphconv_gemm<<<(4 * HWp) / BM, 512, 0, stream>>>(x, wt, bias, tI, tW, out);
}

// Round 4
// 521.796 us; speedup vs baseline: 1.2704x; 1.2704x over previous
//
#include <hip/hip_runtime.h>

// SphereConv2DEXP: grid_sample(bilinear,zeros) + 3x3 conv stride 3 == implicit GEMM
//   M = 131072 (b,ho,wo), N = 256 (cout), K = 1152
// Round 4 = round 3 with the sB fragment-read offset bug fixed (bytes vs
// elements: nt*1024+lane*16 on a __bf16* read past LDS -> NaN).
//  - K ordering k' = (cg, ij, cl): 32-channel groups, 9 ij taps back-to-back
//    per group -> x reuse stays in L2; tap constant per K-step.
//  - LDS in MFMA fragment-chunk order: B pre-tiled by conv_w (linear staging,
//    conflict-free reads); A chunk layout + XOR swizzle.
//  - Epilogue staged through LDS -> 512B-contiguous output rows.

#define Hh   128
#define Ww   256
#define HWp  (Hh*Ww)        // 32768
#define CIN  128
#define COUT 256
#define KTOT 1152
#define NPTS (384*768)
#define BM   128
#define BN   256
#define BK   32
#define NKS  (KTOT/BK)      // 36 = 4 cg * 9 ij

typedef __attribute__((ext_vector_type(8))) __bf16 bf16x8;
typedef __attribute__((ext_vector_type(4))) float  f32x4;

// ---------------------------------------------------------------------------
// Kernel 1: bilinear tap table, [ij][sp] planes (coalesced per-K-step reads).
// ---------------------------------------------------------------------------
__global__ void build_table(const float* __restrict__ grid,
                            int2* __restrict__ tI, float4* __restrict__ tW) {
    int g = blockIdx.x * 256 + threadIdx.x;
    if (g >= NPTS) return;
    int hh = g / 768, ww = g - hh * 768;
    int ho = hh / 3, ii = hh - 3 * ho;
    int wo = ww / 3, jj = ww - 3 * wo;

    float gx = grid[2 * g + 0];
    float gy = grid[2 * g + 1];
    float ix = ((gx + 1.0f) * (float)Ww - 1.0f) * 0.5f;
    float iy = ((gy + 1.0f) * (float)Hh - 1.0f) * 0.5f;
    float x0f = floorf(ix), y0f = floorf(iy);
    int x0 = (int)x0f, y0 = (int)y0f;
    float wx1 = ix - x0f, wx0 = 1.0f - wx1;
    float wy1 = iy - y0f, wy0 = 1.0f - wy1;

    float wyt = (y0 >= 0 && y0 < Hh) ? wy0 : 0.0f;
    float wyb = (y0 + 1 >= 0 && y0 + 1 < Hh) ? wy1 : 0.0f;
    int r0 = min(max(y0, 0), Hh - 1);
    int r1 = min(max(y0 + 1, 0), Hh - 1);

    int xb; float cw0, cw1;
    if (x0 < 0)            { xb = 0;      cw0 = wx1; cw1 = 0.0f; }
    else if (x0 > Ww - 2)  { xb = Ww - 2; cw0 = 0.0f; cw1 = wx0; }
    else                   { xb = x0;     cw0 = wx0; cw1 = wx1; }

    int e = (ii * 3 + jj) * HWp + (ho * Ww + wo);
    tI[e] = make_int2(r0 * Ww + xb, r1 * Ww + xb);
    tW[e] = make_float4(cw0 * wyt, cw1 * wyt, cw0 * wyb, cw1 * wyb);
}

// ---------------------------------------------------------------------------
// Kernel 2: weight f32 -> bf16 in MFMA B-fragment chunk order:
//   wt[ks][nt(16)][chunk(64)][e(8)], chunk=(q,l16): n=nt*16+l16, kk=q*8+e,
//   ks = cg*9+ij, ci = cg*32+kk.
// ---------------------------------------------------------------------------
__global__ void conv_w(const float* __restrict__ w, __bf16* __restrict__ wt) {
    int o = blockIdx.x * 256 + threadIdx.x;   // 294912
    if (o >= NKS * COUT * BK) return;
    int e   = o & 7;
    int chk = (o >> 3) & 63;
    int nt  = (o >> 9) & 15;
    int ks  = o >> 13;
    int q   = chk >> 4, l16 = chk & 15;
    int cg  = ks / 9, ij = ks - cg * 9;
    int n   = nt * 16 + l16;
    int ci  = cg * 32 + q * 8 + e;
    wt[o] = (__bf16)w[n * KTOT + ci * 9 + ij];
}

// ---------------------------------------------------------------------------
// Kernel 3: fused gather + bf16 MFMA GEMM.
// 512 thr (8 waves 2x4), tile 128x256, BK=32, wave tile 64x64, 16x16x32 MFMA.
// LDS: sA 8KB (chunk order + XOR swizzle), sB 16KB (chunk order, linear),
// reused as 33.8KB f32 epilogue staging.
// ---------------------------------------------------------------------------
__global__ __launch_bounds__(512, 4) void sphconv_gemm(
    const float* __restrict__ x, const __bf16* __restrict__ wt,
    const float* __restrict__ bias, const int2* __restrict__ tI,
    const float4* __restrict__ tW, float* __restrict__ out) {

    __shared__ __align__(16) char smem[64 * 132 * 4];   // 33792 B
    __bf16* sA = (__bf16*)smem;                         // 128*32*2 = 8192 B
    __bf16* sB = (__bf16*)(smem + 8192);                // 256*32*2 = 16384 B
    float*  ep = (float*)smem;                          // epilogue reuse

    const int t   = threadIdx.x;
    const int m0  = blockIdx.x * BM;
    const int b   = m0 >> 15;
    const int sp0 = m0 & (HWp - 1);
    const float* xb_ = x + (size_t)b * (CIN * HWp);

    const int lane = t & 63;
    const int wid  = t >> 6;
    const int wrow = wid >> 2;          // 0..1
    const int wcol = wid & 3;           // 0..3
    const int quad = lane >> 4;
    const int l16  = lane & 15;

    const int mr_s = t & 127;           // staging row (fixed sp)
    const int kg   = t >> 7;            // 0..3
    const int sp   = sp0 + mr_s;

    // A staging LDS address: tile mt=mr_s>>4, chunk=(kg*16+(mr_s&15)),
    // XOR-swizzled by (mt&3)<<4.
    const int mtS   = mr_s >> 4;
    const int chkS  = (kg * 16 + (mr_s & 15)) ^ ((mtS & 3) << 4);
    __bf16* sA_dst  = sA + mtS * 512 + chkS * 8;        // element offsets

    f32x4 acc[4][4];
#pragma unroll
    for (int r = 0; r < 4; ++r)
#pragma unroll
        for (int c = 0; c < 4; ++c) {
            f32x4 z = {0.0f, 0.0f, 0.0f, 0.0f};
            acc[r][c] = z;
        }

    for (int cg = 0; cg < 4; ++cg) {
        for (int ij = 0; ij < 9; ++ij) {
            const int ks = cg * 9 + ij;
            const int2   o  = tI[ij * HWp + sp];
            const float4 wv = tW[ij * HWp + sp];

            // B stage: contiguous 16 KB chunk, 32 B/thread (chunk order)
            const __bf16* srcB = wt + ks * (COUT * BK) + t * 16;
            bf16x8 v0 = *(const bf16x8*)(srcB);
            bf16x8 v1 = *(const bf16x8*)(srcB + 8);

            // A gather: 8 consecutive ci planes of group cg, one tap each
            const float* img = xb_ + (size_t)((cg << 5) + (kg << 3)) * HWp;
            bf16x8 av;
#pragma unroll
            for (int j = 0; j < 8; ++j) {
                float2 p0, p1;
                __builtin_memcpy(&p0, img + o.x, 8);
                __builtin_memcpy(&p1, img + o.y, 8);
                av[j] = (__bf16)(p0.x * wv.x + p0.y * wv.y +
                                 p1.x * wv.z + p1.y * wv.w);
                img += HWp;
            }

            *(bf16x8*)sA_dst            = av;
            *(bf16x8*)(sB + t * 16)     = v0;
            *(bf16x8*)(sB + t * 16 + 8) = v1;
            __syncthreads();

            // fragment reads: base + lane*8 elements (16 B) — conflict-free
            bf16x8 af[4], bfr[4];
#pragma unroll
            for (int r = 0; r < 4; ++r) {
                int mt = wrow * 4 + r;
                af[r] = *(const bf16x8*)(sA + mt * 512 +
                                         ((lane ^ ((mt & 3) << 4)) * 8));
            }
#pragma unroll
            for (int c = 0; c < 4; ++c) {
                int nt = wcol * 4 + c;
                bfr[c] = *(const bf16x8*)(sB + nt * 512 + lane * 8);  // FIXED
            }
#pragma unroll
            for (int r = 0; r < 4; ++r)
#pragma unroll
                for (int c = 0; c < 4; ++c)
                    acc[r][c] = __builtin_amdgcn_mfma_f32_16x16x32_bf16(
                        af[r], bfr[c], acc[r][c], 0, 0, 0);
            __syncthreads();
        }
    }

    // ---- epilogue: stage through LDS for 512B-contiguous output rows ----
    // acc[r][c][i] = C[m = wrow*64+r*16+quad*4+i][n = wcol*64+c*16+l16]
    const int n_loc = wcol * 16 + l16;          // 0..63 per c-pass
    for (int c = 0; c < 4; ++c) {
        float bvc = bias[wcol * 64 + c * 16 + l16];
#pragma unroll
        for (int r = 0; r < 4; ++r) {
            int m = wrow * 64 + r * 16 + quad * 4;
            f32x4 v = acc[r][c];
            float* d = ep + n_loc * 132 + m;
            d[0] = v[0] + bvc; d[1] = v[1] + bvc;
            d[2] = v[2] + bvc; d[3] = v[3] + bvc;
        }
        __syncthreads();
        {
            int n2 = t >> 3;                    // 0..63
            int mp = (t & 7) * 16;              // 0..112
            int n  = (n2 >> 4) * 64 + c * 16 + (n2 & 15);
            float* dst = out + (((size_t)(b * COUT + n)) << 15) + sp0 + mp;
            const float* src = ep + n2 * 132 + mp;
#pragma unroll
            for (int k4 = 0; k4 < 4; ++k4) {
                float4 v = *(const float4*)(src + k4 * 4);
                *(float4*)(dst + k4 * 4) = v;
            }
        }
        __syncthreads();
    }
}

// ---------------------------------------------------------------------------
extern "C" void kernel_launch(void* const* d_in, const int* in_sizes, int n_in,
                              void* d_out, int out_size, void* d_ws, size_t ws_size,
                              hipStream_t stream) {
    const float* x    = (const float*)d_in[0];
    const float* w    = (const float*)d_in[1];
    const float* bias = (const float*)d_in[2];
    const float* grid = (const float*)d_in[3];
    float* out = (float*)d_out;

    char* ws = (char*)d_ws;
    int2*   tI = (int2*)(ws);                       // 2359296 B
    float4* tW = (float4*)(ws + 2359296);           // 4718592 B
    __bf16* wt = (__bf16*)(ws + 7077888);           //  589824 B

    build_table<<<(NPTS + 255) / 256, 256, 0, stream>>>(grid, tI, tW);
    conv_w<<<(NKS * COUT * BK + 255) / 256, 256, 0, stream>>>(w, wt);
    sphconv_gemm<<<(4 * HWp) / BM, 512, 0, stream>>>(x, wt, bias, tI, tW, out);
}